// Round 1
// baseline (258.919 us; speedup 1.0000x reference)
//
#include <hip/hip_runtime.h>

// ---------------------------------------------------------------------------
// StandardMultiHeadAttention: B=2, S=2048, D=1024, H=16, Dh=64, causal.
// Pipeline: fp32->f16 convert -> QKV GEMM (MFMA) -> flash attention (MFMA)
//           -> output GEMM (MFMA, fp32 out).
// Workspace layout (48 MB total):
//   [0,8M)    xb   : x as f16 [4096,1024]
//   [8M,16M)  wb   : Wq,Wk,Wv,Wo as f16, 2MB each (row=out, K-major)
//   [16M,40M) qkv  : Q [B,H,S,64] (pre-scaled by 0.125), K [B,H,S,64],
//                    Vt [B,H,64,S], f16, 8MB each
//   [40M,48M) ob   : attention output [B,S,1024] f16
// ---------------------------------------------------------------------------

typedef _Float16 f16x8 __attribute__((ext_vector_type(8)));
typedef _Float16 f16x4 __attribute__((ext_vector_type(4)));
typedef float f32x4 __attribute__((ext_vector_type(4)));

#define S_  2048
#define DM  1024
#define NH  16
#define DH  64

__device__ __forceinline__ void gload_lds16(const void* g, void* s) {
  __builtin_amdgcn_global_load_lds(
      (const __attribute__((address_space(1))) void*)g,
      (__attribute__((address_space(3))) void*)s, 16, 0, 0);
}

// ----------------------------- convert kernels -----------------------------

__global__ void cvt_x_kernel(const float* __restrict__ src,
                             _Float16* __restrict__ dst) {
  const int i = blockIdx.x * 256 + threadIdx.x;   // exact: 4096*256 float4s
  const float4 v = ((const float4*)src)[i];
  f16x4 h;
  h[0] = (_Float16)v.x; h[1] = (_Float16)v.y;
  h[2] = (_Float16)v.z; h[3] = (_Float16)v.w;
  ((f16x4*)dst)[i] = h;
}

__global__ void cvt_w_kernel(const float* __restrict__ w0,
                             const float* __restrict__ w1,
                             const float* __restrict__ w2,
                             const float* __restrict__ w3,
                             _Float16* __restrict__ dst) {
  const int y = blockIdx.y;
  const float* src = (y == 0) ? w0 : (y == 1) ? w1 : (y == 2) ? w2 : w3;
  const int i = blockIdx.x * 256 + threadIdx.x;   // exact: 1024*256 float4s
  const float4 v = ((const float4*)src)[i];
  f16x4 h;
  h[0] = (_Float16)v.x; h[1] = (_Float16)v.y;
  h[2] = (_Float16)v.z; h[3] = (_Float16)v.w;
  ((f16x4*)(dst + (size_t)y * (DM * DM)))[i] = h;
}

// ------------------------------- GEMM core ---------------------------------
// C[128,128] += A[128x1024] * W[128x1024]^T  (both K-major, f16).
// m97 structure: 128x128 tile, BK=32, global_load_lds width 16, 2 barriers.

__device__ __forceinline__ void gemm_core_k1024(
    const _Float16* __restrict__ A, const _Float16* __restrict__ W,
    _Float16* As, _Float16* Ws, f32x4 acc[4][4], int m0, int n0)
{
  const int t = threadIdx.x;
  const int w = t >> 6, l = t & 63;
  const int quad = l >> 4, ln = l & 15;
  const int wm = (w >> 1) << 6, wn = (w & 1) << 6;
  const int srow = l >> 2, scol = (l & 3) << 3;

  for (int k0 = 0; k0 < DM; k0 += 32) {
#pragma unroll
    for (int i = 0; i < 2; ++i) {
      const int ra = w * 32 + i * 16;   // 16 rows per wave-issue
      gload_lds16(&A[(size_t)(m0 + ra + srow) * DM + k0 + scol], &As[ra * 32]);
      gload_lds16(&W[(size_t)(n0 + ra + srow) * DM + k0 + scol], &Ws[ra * 32]);
    }
    __syncthreads();   // drains vmcnt -> staged tiles visible

    f16x8 af[4], bf[4];
#pragma unroll
    for (int mi = 0; mi < 4; ++mi)
      af[mi] = *(const f16x8*)&As[(wm + mi * 16 + ln) * 32 + quad * 8];
#pragma unroll
    for (int ni = 0; ni < 4; ++ni)
      bf[ni] = *(const f16x8*)&Ws[(wn + ni * 16 + ln) * 32 + quad * 8];
#pragma unroll
    for (int mi = 0; mi < 4; ++mi)
#pragma unroll
      for (int ni = 0; ni < 4; ++ni)
        acc[mi][ni] = __builtin_amdgcn_mfma_f32_16x16x32_f16(
            af[mi], bf[ni], acc[mi][ni], 0, 0, 0);
    __syncthreads();   // before next stage overwrites LDS
  }
}

// z=0: Q (bias, *0.125, [B,H,S,64]); z=1: K (bias, [B,H,S,64]);
// z=2: V (bias, transposed [B,H,64,S])
__global__ __launch_bounds__(256, 2) void gemm_qkv_kernel(
    const _Float16* __restrict__ xb, const _Float16* __restrict__ wb,
    const float* __restrict__ bq, const float* __restrict__ bk,
    const float* __restrict__ bv, _Float16* __restrict__ qkv)
{
  __shared__ _Float16 As[128 * 32];
  __shared__ _Float16 Ws[128 * 32];
  const int z = blockIdx.z;
  const _Float16* W = wb + (size_t)z * (DM * DM);
  const float* bias = (z == 0) ? bq : ((z == 1) ? bk : bv);
  _Float16* out = qkv + (size_t)z * (4096 * DM / NH * NH); // 4096*1024 elems

  const f32x4 z4 = {0.f, 0.f, 0.f, 0.f};
  f32x4 acc[4][4];
#pragma unroll
  for (int mi = 0; mi < 4; ++mi)
#pragma unroll
    for (int ni = 0; ni < 4; ++ni) acc[mi][ni] = z4;

  const int m0 = blockIdx.y * 128, n0 = blockIdx.x * 128;
  gemm_core_k1024(xb, W, As, Ws, acc, m0, n0);

  const int t = threadIdx.x, w = t >> 6, l = t & 63;
  const int quad = l >> 4, ln = l & 15;
  const int wm = (w >> 1) << 6, wn = (w & 1) << 6;
  const float scale = (z == 0) ? 0.125f : 1.0f;   // 1/sqrt(Dh) folded into Q

#pragma unroll
  for (int ni = 0; ni < 4; ++ni) {
    const int c = n0 + wn + ni * 16 + ln;
    const float bias_c = bias[c];
    const int h = c >> 6, d = c & 63;
#pragma unroll
    for (int mi = 0; mi < 4; ++mi) {
      const int mb = m0 + wm + mi * 16 + quad * 4;
#pragma unroll
      for (int r = 0; r < 4; ++r) {
        const int mg = mb + r;
        const int b = mg >> 11, s = mg & 2047;
        const float v = (acc[mi][ni][r] + bias_c) * scale;
        if (z == 2)
          out[((size_t)(b * NH + h) * DH + d) * S_ + s] = (_Float16)v;
        else
          out[((size_t)(b * NH + h) * S_ + s) * DH + d] = (_Float16)v;
      }
    }
  }
}

__global__ __launch_bounds__(256, 2) void gemm_out_kernel(
    const _Float16* __restrict__ ob, const _Float16* __restrict__ wo,
    const float* __restrict__ bo, float* __restrict__ out)
{
  __shared__ _Float16 As[128 * 32];
  __shared__ _Float16 Ws[128 * 32];
  const f32x4 z4 = {0.f, 0.f, 0.f, 0.f};
  f32x4 acc[4][4];
#pragma unroll
  for (int mi = 0; mi < 4; ++mi)
#pragma unroll
    for (int ni = 0; ni < 4; ++ni) acc[mi][ni] = z4;

  const int m0 = blockIdx.y * 128, n0 = blockIdx.x * 128;
  gemm_core_k1024(ob, wo, As, Ws, acc, m0, n0);

  const int t = threadIdx.x, w = t >> 6, l = t & 63;
  const int quad = l >> 4, ln = l & 15;
  const int wm = (w >> 1) << 6, wn = (w & 1) << 6;

#pragma unroll
  for (int ni = 0; ni < 4; ++ni) {
    const int c = n0 + wn + ni * 16 + ln;
    const float bias_c = bo[c];
#pragma unroll
    for (int mi = 0; mi < 4; ++mi) {
      const int mb = m0 + wm + mi * 16 + quad * 4;
#pragma unroll
      for (int r = 0; r < 4; ++r)
        out[(size_t)(mb + r) * DM + c] = acc[mi][ni][r] + bias_c;
    }
  }
}

// ---------------------------- flash attention ------------------------------
// grid (16 q-blocks of 128, 32 bh). 4 waves, each owns 32 q rows.
// KV tiles of 64. Q frags in registers. P via padded LDS (stride 72 -> 2-way
// bank aliasing only, which is free). Online softmax in fp32.

__global__ __launch_bounds__(256, 2) void attn_kernel(
    const _Float16* __restrict__ Qb, const _Float16* __restrict__ Kb,
    const _Float16* __restrict__ Vtb, _Float16* __restrict__ Ob)
{
  __shared__ _Float16 Ks[64 * 72];   // [kv][d]
  __shared__ _Float16 Vs[64 * 72];   // [d][kv]
  __shared__ _Float16 Ps[128 * 72];  // [q][kv], per-wave private rows

  const int qb0 = blockIdx.x * 128;
  const int bh = blockIdx.y;
  const int bidx = bh >> 4, h = bh & 15;
  const _Float16* Qh = Qb + (size_t)bh * (S_ * DH);
  const _Float16* Kh = Kb + (size_t)bh * (S_ * DH);
  const _Float16* Vh = Vtb + (size_t)bh * (DH * S_);

  const int t = threadIdx.x, w = t >> 6, l = t & 63;
  const int quad = l >> 4, ln = l & 15;

  // Q fragments (A-operand layout): rows qb0+w*32+mi*16+ln, k=ks*32+quad*8
  f16x8 qf[2][2];
#pragma unroll
  for (int mi = 0; mi < 2; ++mi)
#pragma unroll
    for (int ks = 0; ks < 2; ++ks)
      qf[mi][ks] = *(const f16x8*)
          &Qh[(size_t)(qb0 + w * 32 + mi * 16 + ln) * DH + ks * 32 + quad * 8];

  const f32x4 z4 = {0.f, 0.f, 0.f, 0.f};
  f32x4 oacc[2][4];
  float m_i[2][4], l_i[2][4];
#pragma unroll
  for (int mi = 0; mi < 2; ++mi) {
#pragma unroll
    for (int di = 0; di < 4; ++di) oacc[mi][di] = z4;
#pragma unroll
    for (int r = 0; r < 4; ++r) { m_i[mi][r] = -__builtin_inff(); l_i[mi][r] = 0.f; }
  }

  const int sr = t >> 3;          // staging row 0..31
  const int sc = (t & 7) << 3;    // staging col 0,8,..,56

  for (int kb = 0; kb < qb0 + 128; kb += 64) {
    // stage K tile [64][64] and Vt tile [64][64] (16B loads + b128 writes)
#pragma unroll
    for (int p = 0; p < 2; ++p) {
      const int r = sr + p * 32;
      *(f16x8*)&Ks[r * 72 + sc] = *(const f16x8*)&Kh[(size_t)(kb + r) * DH + sc];
      *(f16x8*)&Vs[r * 72 + sc] = *(const f16x8*)&Vh[(size_t)r * S_ + kb + sc];
    }
    __syncthreads();

    // S = Q K^T  (pre-scaled by 0.125 via Q)
    f32x4 sacc[2][4];
#pragma unroll
    for (int mi = 0; mi < 2; ++mi)
#pragma unroll
      for (int ni = 0; ni < 4; ++ni) sacc[mi][ni] = z4;

#pragma unroll
    for (int ks = 0; ks < 2; ++ks) {
      f16x8 kf[4];
#pragma unroll
      for (int ni = 0; ni < 4; ++ni)
        kf[ni] = *(const f16x8*)&Ks[(ni * 16 + ln) * 72 + ks * 32 + quad * 8];
#pragma unroll
      for (int mi = 0; mi < 2; ++mi)
#pragma unroll
        for (int ni = 0; ni < 4; ++ni)
          sacc[mi][ni] = __builtin_amdgcn_mfma_f32_16x16x32_f16(
              qf[mi][ks], kf[ni], sacc[mi][ni], 0, 0, 0);
    }

    // causal mask: only tiles with kb >= qb0 touch the diagonal
    if (kb >= qb0) {
#pragma unroll
      for (int mi = 0; mi < 2; ++mi) {
        const int q = qb0 + w * 32 + mi * 16 + quad * 4;
#pragma unroll
        for (int ni = 0; ni < 4; ++ni) {
          const int kv = kb + ni * 16 + ln;
#pragma unroll
          for (int r = 0; r < 4; ++r)
            if (kv > q + r) sacc[mi][ni][r] = -__builtin_inff();
        }
      }
    }

    // online softmax per row (row = quad*4+r within tile mi)
#pragma unroll
    for (int mi = 0; mi < 2; ++mi) {
      const int prow = (w * 32 + mi * 16 + quad * 4) * 72;
#pragma unroll
      for (int r = 0; r < 4; ++r) {
        float v = fmaxf(fmaxf(sacc[mi][0][r], sacc[mi][1][r]),
                        fmaxf(sacc[mi][2][r], sacc[mi][3][r]));
#pragma unroll
        for (int off = 1; off < 16; off <<= 1) v = fmaxf(v, __shfl_xor(v, off));
        const float mnew = fmaxf(m_i[mi][r], v);
        const float alpha = __expf(m_i[mi][r] - mnew);  // -inf -> 0 first time
        m_i[mi][r] = mnew;
        float rs = 0.f;
#pragma unroll
        for (int ni = 0; ni < 4; ++ni) {
          const float p_ = __expf(sacc[mi][ni][r] - mnew);
          sacc[mi][ni][r] = p_;
          rs += p_;
        }
#pragma unroll
        for (int off = 1; off < 16; off <<= 1) rs += __shfl_xor(rs, off);
        l_i[mi][r] = l_i[mi][r] * alpha + rs;
#pragma unroll
        for (int di = 0; di < 4; ++di) oacc[mi][di][r] *= alpha;
        // P -> LDS (C/D layout scatter; wave-private rows, no barrier needed)
#pragma unroll
        for (int ni = 0; ni < 4; ++ni)
          Ps[prow + r * 72 + ni * 16 + ln] = (_Float16)sacc[mi][ni][r];
      }
    }

    // O += P * V
#pragma unroll
    for (int ks = 0; ks < 2; ++ks) {
      f16x8 pf[2], vf[4];
#pragma unroll
      for (int mi = 0; mi < 2; ++mi)
        pf[mi] = *(const f16x8*)&Ps[(w * 32 + mi * 16 + ln) * 72 + ks * 32 + quad * 8];
#pragma unroll
      for (int di = 0; di < 4; ++di)
        vf[di] = *(const f16x8*)&Vs[(di * 16 + ln) * 72 + ks * 32 + quad * 8];
#pragma unroll
      for (int mi = 0; mi < 2; ++mi)
#pragma unroll
        for (int di = 0; di < 4; ++di)
          oacc[mi][di] = __builtin_amdgcn_mfma_f32_16x16x32_f16(
              pf[mi], vf[di], oacc[mi][di], 0, 0, 0);
    }
    __syncthreads();  // before next tile overwrites Ks/Vs
  }

  // epilogue: O /= l, write [B,S,H*64] f16
#pragma unroll
  for (int mi = 0; mi < 2; ++mi)
#pragma unroll
    for (int r = 0; r < 4; ++r) {
      const float inv = 1.0f / l_i[mi][r];
      const int q = qb0 + w * 32 + mi * 16 + quad * 4 + r;
      _Float16* orow = Ob + (size_t)(bidx * S_ + q) * DM + h * DH;
#pragma unroll
      for (int di = 0; di < 4; ++di)
        orow[di * 16 + ln] = (_Float16)(oacc[mi][di][r] * inv);
    }
}

// ------------------------------- launcher ----------------------------------

extern "C" void kernel_launch(void* const* d_in, const int* in_sizes, int n_in,
                              void* d_out, int out_size, void* d_ws, size_t ws_size,
                              hipStream_t stream) {
  (void)in_sizes; (void)n_in; (void)out_size; (void)ws_size;
  const float* x  = (const float*)d_in[0];
  const float* Wq = (const float*)d_in[1];
  const float* bq = (const float*)d_in[2];
  const float* Wk = (const float*)d_in[3];
  const float* bk = (const float*)d_in[4];
  const float* Wv = (const float*)d_in[5];
  const float* bv = (const float*)d_in[6];
  const float* Wo = (const float*)d_in[7];
  const float* bo = (const float*)d_in[8];

  char* ws = (char*)d_ws;
  _Float16* xb  = (_Float16*)(ws);                      // 8 MB
  _Float16* wb  = (_Float16*)(ws + (8u << 20));         // 4 x 2 MB
  _Float16* qkv = (_Float16*)(ws + (16u << 20));        // Q,K,Vt 8 MB each
  _Float16* ob  = (_Float16*)(ws + (40u << 20));        // 8 MB

  cvt_x_kernel<<<dim3(4096), dim3(256), 0, stream>>>(x, xb);
  cvt_w_kernel<<<dim3(1024, 4), dim3(256), 0, stream>>>(Wq, Wk, Wv, Wo, wb);
  gemm_qkv_kernel<<<dim3(8, 32, 3), dim3(256), 0, stream>>>(xb, wb, bq, bk, bv, qkv);
  attn_kernel<<<dim3(16, 32), dim3(256), 0, stream>>>(
      qkv, qkv + (size_t)4096 * DM, qkv + (size_t)2 * 4096 * DM, ob);
  gemm_out_kernel<<<dim3(8, 32), dim3(256), 0, stream>>>(
      ob, wb + (size_t)3 * DM * DM, bo, (float*)d_out);
}

// Round 2
// 225.134 us; speedup vs baseline: 1.1501x; 1.1501x over previous
//
#include <hip/hip_runtime.h>

// ---------------------------------------------------------------------------
// StandardMultiHeadAttention: B=2, S=2048, D=1024, H=16, Dh=64, causal.
// Pipeline: fp32->f16 convert -> QKV GEMM (MFMA) -> flash attention (MFMA)
//           -> output GEMM (MFMA, fp32 out).
// Workspace layout (48 MB total):
//   [0,8M)    xb   : x as f16 [4096,1024]
//   [8M,16M)  wb   : Wq,Wk,Wv,Wo as f16, 2MB each (row=out, K-major)
//   [16M,40M) qkv  : Q [B,H,S,64] (pre-scaled by 0.125), K [B,H,S,64],
//                    Vt [B,H,64,S], f16, 8MB each
//   [40M,48M) ob   : attention output [B,S,1024] f16
//
// R1: attn rebalanced — 64-row q blocks (1024 blocks = 4/CU), reversed
//     dispatch so longest (most KV tiles) blocks go first, Ps stride 68
//     to kill 4-way bank conflicts. Theory: latency/occupancy-bound at
//     11% occupancy with 16x causal work imbalance.
// ---------------------------------------------------------------------------

typedef _Float16 f16x8 __attribute__((ext_vector_type(8)));
typedef _Float16 f16x4 __attribute__((ext_vector_type(4)));
typedef float f32x4 __attribute__((ext_vector_type(4)));

#define S_  2048
#define DM  1024
#define NH  16
#define DH  64

__device__ __forceinline__ void gload_lds16(const void* g, void* s) {
  __builtin_amdgcn_global_load_lds(
      (const __attribute__((address_space(1))) void*)g,
      (__attribute__((address_space(3))) void*)s, 16, 0, 0);
}

// ----------------------------- convert kernels -----------------------------

__global__ void cvt_x_kernel(const float* __restrict__ src,
                             _Float16* __restrict__ dst) {
  const int i = blockIdx.x * 256 + threadIdx.x;   // exact: 4096*256 float4s
  const float4 v = ((const float4*)src)[i];
  f16x4 h;
  h[0] = (_Float16)v.x; h[1] = (_Float16)v.y;
  h[2] = (_Float16)v.z; h[3] = (_Float16)v.w;
  ((f16x4*)dst)[i] = h;
}

__global__ void cvt_w_kernel(const float* __restrict__ w0,
                             const float* __restrict__ w1,
                             const float* __restrict__ w2,
                             const float* __restrict__ w3,
                             _Float16* __restrict__ dst) {
  const int y = blockIdx.y;
  const float* src = (y == 0) ? w0 : (y == 1) ? w1 : (y == 2) ? w2 : w3;
  const int i = blockIdx.x * 256 + threadIdx.x;   // exact: 1024*256 float4s
  const float4 v = ((const float4*)src)[i];
  f16x4 h;
  h[0] = (_Float16)v.x; h[1] = (_Float16)v.y;
  h[2] = (_Float16)v.z; h[3] = (_Float16)v.w;
  ((f16x4*)(dst + (size_t)y * (DM * DM)))[i] = h;
}

// ------------------------------- GEMM core ---------------------------------
// C[128,128] += A[128x1024] * W[128x1024]^T  (both K-major, f16).
// m97 structure: 128x128 tile, BK=32, global_load_lds width 16, 2 barriers.

__device__ __forceinline__ void gemm_core_k1024(
    const _Float16* __restrict__ A, const _Float16* __restrict__ W,
    _Float16* As, _Float16* Ws, f32x4 acc[4][4], int m0, int n0)
{
  const int t = threadIdx.x;
  const int w = t >> 6, l = t & 63;
  const int quad = l >> 4, ln = l & 15;
  const int wm = (w >> 1) << 6, wn = (w & 1) << 6;
  const int srow = l >> 2, scol = (l & 3) << 3;

  for (int k0 = 0; k0 < DM; k0 += 32) {
#pragma unroll
    for (int i = 0; i < 2; ++i) {
      const int ra = w * 32 + i * 16;   // 16 rows per wave-issue
      gload_lds16(&A[(size_t)(m0 + ra + srow) * DM + k0 + scol], &As[ra * 32]);
      gload_lds16(&W[(size_t)(n0 + ra + srow) * DM + k0 + scol], &Ws[ra * 32]);
    }
    __syncthreads();   // drains vmcnt -> staged tiles visible

    f16x8 af[4], bf[4];
#pragma unroll
    for (int mi = 0; mi < 4; ++mi)
      af[mi] = *(const f16x8*)&As[(wm + mi * 16 + ln) * 32 + quad * 8];
#pragma unroll
    for (int ni = 0; ni < 4; ++ni)
      bf[ni] = *(const f16x8*)&Ws[(wn + ni * 16 + ln) * 32 + quad * 8];
#pragma unroll
    for (int mi = 0; mi < 4; ++mi)
#pragma unroll
      for (int ni = 0; ni < 4; ++ni)
        acc[mi][ni] = __builtin_amdgcn_mfma_f32_16x16x32_f16(
            af[mi], bf[ni], acc[mi][ni], 0, 0, 0);
    __syncthreads();   // before next stage overwrites LDS
  }
}

// z=0: Q (bias, *0.125, [B,H,S,64]); z=1: K (bias, [B,H,S,64]);
// z=2: V (bias, transposed [B,H,64,S])
__global__ __launch_bounds__(256, 2) void gemm_qkv_kernel(
    const _Float16* __restrict__ xb, const _Float16* __restrict__ wb,
    const float* __restrict__ bq, const float* __restrict__ bk,
    const float* __restrict__ bv, _Float16* __restrict__ qkv)
{
  __shared__ _Float16 As[128 * 32];
  __shared__ _Float16 Ws[128 * 32];
  const int z = blockIdx.z;
  const _Float16* W = wb + (size_t)z * (DM * DM);
  const float* bias = (z == 0) ? bq : ((z == 1) ? bk : bv);
  _Float16* out = qkv + (size_t)z * ((size_t)4096 * DM);

  const f32x4 z4 = {0.f, 0.f, 0.f, 0.f};
  f32x4 acc[4][4];
#pragma unroll
  for (int mi = 0; mi < 4; ++mi)
#pragma unroll
    for (int ni = 0; ni < 4; ++ni) acc[mi][ni] = z4;

  const int m0 = blockIdx.y * 128, n0 = blockIdx.x * 128;
  gemm_core_k1024(xb, W, As, Ws, acc, m0, n0);

  const int t = threadIdx.x, w = t >> 6, l = t & 63;
  const int quad = l >> 4, ln = l & 15;
  const int wm = (w >> 1) << 6, wn = (w & 1) << 6;
  const float scale = (z == 0) ? 0.125f : 1.0f;   // 1/sqrt(Dh) folded into Q

#pragma unroll
  for (int ni = 0; ni < 4; ++ni) {
    const int c = n0 + wn + ni * 16 + ln;
    const float bias_c = bias[c];
    const int h = c >> 6, d = c & 63;
#pragma unroll
    for (int mi = 0; mi < 4; ++mi) {
      const int mb = m0 + wm + mi * 16 + quad * 4;
#pragma unroll
      for (int r = 0; r < 4; ++r) {
        const int mg = mb + r;
        const int b = mg >> 11, s = mg & 2047;
        const float v = (acc[mi][ni][r] + bias_c) * scale;
        if (z == 2)
          out[((size_t)(b * NH + h) * DH + d) * S_ + s] = (_Float16)v;
        else
          out[((size_t)(b * NH + h) * S_ + s) * DH + d] = (_Float16)v;
      }
    }
  }
}

__global__ __launch_bounds__(256, 2) void gemm_out_kernel(
    const _Float16* __restrict__ ob, const _Float16* __restrict__ wo,
    const float* __restrict__ bo, float* __restrict__ out)
{
  __shared__ _Float16 As[128 * 32];
  __shared__ _Float16 Ws[128 * 32];
  const f32x4 z4 = {0.f, 0.f, 0.f, 0.f};
  f32x4 acc[4][4];
#pragma unroll
  for (int mi = 0; mi < 4; ++mi)
#pragma unroll
    for (int ni = 0; ni < 4; ++ni) acc[mi][ni] = z4;

  const int m0 = blockIdx.y * 128, n0 = blockIdx.x * 128;
  gemm_core_k1024(ob, wo, As, Ws, acc, m0, n0);

  const int t = threadIdx.x, w = t >> 6, l = t & 63;
  const int quad = l >> 4, ln = l & 15;
  const int wm = (w >> 1) << 6, wn = (w & 1) << 6;

#pragma unroll
  for (int ni = 0; ni < 4; ++ni) {
    const int c = n0 + wn + ni * 16 + ln;
    const float bias_c = bo[c];
#pragma unroll
    for (int mi = 0; mi < 4; ++mi) {
      const int mb = m0 + wm + mi * 16 + quad * 4;
#pragma unroll
      for (int r = 0; r < 4; ++r)
        out[(size_t)(mb + r) * DM + c] = acc[mi][ni][r] + bias_c;
    }
  }
}

// ---------------------------- flash attention ------------------------------
// R1: grid (bh=32, qi=32 reversed). 64 q rows/block, 4 waves, each wave owns
// one 16-row MFMA tile. KV tiles of 64; only the kb==qb0 tile needs masking.
// Q frags in registers; P via LDS stride 68 (2-way bank aliasing = free).

__global__ __launch_bounds__(256, 4) void attn_kernel(
    const _Float16* __restrict__ Qb, const _Float16* __restrict__ Kb,
    const _Float16* __restrict__ Vtb, _Float16* __restrict__ Ob)
{
  __shared__ _Float16 Ks[64 * 72];   // [kv][d]
  __shared__ _Float16 Vs[64 * 72];   // [d][kv]
  __shared__ _Float16 Ps[64 * 68];   // [q][kv], wave-private rows

  const int qi = 31 - blockIdx.y;    // longest blocks (most KV tiles) first
  const int qb0 = qi << 6;
  const int bh = blockIdx.x;
  const int bidx = bh >> 4, h = bh & 15;
  const _Float16* Qh = Qb + (size_t)bh * (S_ * DH);
  const _Float16* Kh = Kb + (size_t)bh * (S_ * DH);
  const _Float16* Vh = Vtb + (size_t)bh * (DH * S_);

  const int t = threadIdx.x, w = t >> 6, l = t & 63;
  const int quad = l >> 4, ln = l & 15;

  // Q fragments (A-operand layout): row qb0+w*16+ln, k=ks*32+quad*8
  f16x8 qf[2];
#pragma unroll
  for (int ks = 0; ks < 2; ++ks)
    qf[ks] = *(const f16x8*)
        &Qh[(size_t)(qb0 + w * 16 + ln) * DH + ks * 32 + quad * 8];

  const f32x4 z4 = {0.f, 0.f, 0.f, 0.f};
  f32x4 oacc[4];
  float m_i[4], l_i[4];
#pragma unroll
  for (int di = 0; di < 4; ++di) oacc[di] = z4;
#pragma unroll
  for (int r = 0; r < 4; ++r) { m_i[r] = -__builtin_inff(); l_i[r] = 0.f; }

  const int sr = t >> 3;          // staging row 0..31
  const int sc = (t & 7) << 3;    // staging col 0,8,..,56

  for (int kb = 0; kb <= qb0; kb += 64) {
    // stage K tile [64][64] and Vt tile [64][64]
#pragma unroll
    for (int p = 0; p < 2; ++p) {
      const int r = sr + p * 32;
      *(f16x8*)&Ks[r * 72 + sc] = *(const f16x8*)&Kh[(size_t)(kb + r) * DH + sc];
      *(f16x8*)&Vs[r * 72 + sc] = *(const f16x8*)&Vh[(size_t)r * S_ + kb + sc];
    }
    __syncthreads();

    // S = Q K^T  (pre-scaled by 0.125 via Q)
    f32x4 sacc[4];
#pragma unroll
    for (int ni = 0; ni < 4; ++ni) sacc[ni] = z4;

#pragma unroll
    for (int ks = 0; ks < 2; ++ks) {
      f16x8 kf[4];
#pragma unroll
      for (int ni = 0; ni < 4; ++ni)
        kf[ni] = *(const f16x8*)&Ks[(ni * 16 + ln) * 72 + ks * 32 + quad * 8];
#pragma unroll
      for (int ni = 0; ni < 4; ++ni)
        sacc[ni] = __builtin_amdgcn_mfma_f32_16x16x32_f16(
            qf[ks], kf[ni], sacc[ni], 0, 0, 0);
    }

    // causal mask: only the diagonal tile
    if (kb == qb0) {
      const int q = qb0 + w * 16 + quad * 4;
#pragma unroll
      for (int ni = 0; ni < 4; ++ni) {
        const int kv = kb + ni * 16 + ln;
#pragma unroll
        for (int r = 0; r < 4; ++r)
          if (kv > q + r) sacc[ni][r] = -__builtin_inff();
      }
    }

    // online softmax per row (row = quad*4+r within this wave's 16-row tile)
    {
      const int prow = (w * 16 + quad * 4) * 68;
#pragma unroll
      for (int r = 0; r < 4; ++r) {
        float v = fmaxf(fmaxf(sacc[0][r], sacc[1][r]),
                        fmaxf(sacc[2][r], sacc[3][r]));
#pragma unroll
        for (int off = 1; off < 16; off <<= 1) v = fmaxf(v, __shfl_xor(v, off));
        const float mnew = fmaxf(m_i[r], v);
        const float alpha = __expf(m_i[r] - mnew);  // -inf -> 0 first time
        m_i[r] = mnew;
        float rs = 0.f;
#pragma unroll
        for (int ni = 0; ni < 4; ++ni) {
          const float p_ = __expf(sacc[ni][r] - mnew);
          sacc[ni][r] = p_;
          rs += p_;
        }
#pragma unroll
        for (int off = 1; off < 16; off <<= 1) rs += __shfl_xor(rs, off);
        l_i[r] = l_i[r] * alpha + rs;
#pragma unroll
        for (int di = 0; di < 4; ++di) oacc[di][r] *= alpha;
        // P -> LDS (C/D layout scatter; wave-private rows, no barrier needed)
#pragma unroll
        for (int ni = 0; ni < 4; ++ni)
          Ps[prow + r * 68 + ni * 16 + ln] = (_Float16)sacc[ni][r];
      }
    }

    // O += P * V
#pragma unroll
    for (int ks = 0; ks < 2; ++ks) {
      f16x8 pf, vf[4];
      pf = *(const f16x8*)&Ps[(w * 16 + ln) * 68 + ks * 32 + quad * 8];
#pragma unroll
      for (int di = 0; di < 4; ++di)
        vf[di] = *(const f16x8*)&Vs[(di * 16 + ln) * 72 + ks * 32 + quad * 8];
#pragma unroll
      for (int di = 0; di < 4; ++di)
        oacc[di] = __builtin_amdgcn_mfma_f32_16x16x32_f16(
            pf, vf[di], oacc[di], 0, 0, 0);
    }
    __syncthreads();  // before next tile overwrites Ks/Vs
  }

  // epilogue: O /= l, write [B,S,H*64] f16
#pragma unroll
  for (int r = 0; r < 4; ++r) {
    const float inv = 1.0f / l_i[r];
    const int q = qb0 + w * 16 + quad * 4 + r;
    _Float16* orow = Ob + (size_t)(bidx * S_ + q) * DM + h * DH;
#pragma unroll
    for (int di = 0; di < 4; ++di)
      orow[di * 16 + ln] = (_Float16)(oacc[di][r] * inv);
  }
}

// ------------------------------- launcher ----------------------------------

extern "C" void kernel_launch(void* const* d_in, const int* in_sizes, int n_in,
                              void* d_out, int out_size, void* d_ws, size_t ws_size,
                              hipStream_t stream) {
  (void)in_sizes; (void)n_in; (void)out_size; (void)ws_size;
  const float* x  = (const float*)d_in[0];
  const float* Wq = (const float*)d_in[1];
  const float* bq = (const float*)d_in[2];
  const float* Wk = (const float*)d_in[3];
  const float* bk = (const float*)d_in[4];
  const float* Wv = (const float*)d_in[5];
  const float* bv = (const float*)d_in[6];
  const float* Wo = (const float*)d_in[7];
  const float* bo = (const float*)d_in[8];

  char* ws = (char*)d_ws;
  _Float16* xb  = (_Float16*)(ws);                      // 8 MB
  _Float16* wb  = (_Float16*)(ws + (8u << 20));         // 4 x 2 MB
  _Float16* qkv = (_Float16*)(ws + (16u << 20));        // Q,K,Vt 8 MB each
  _Float16* ob  = (_Float16*)(ws + (40u << 20));        // 8 MB

  cvt_x_kernel<<<dim3(4096), dim3(256), 0, stream>>>(x, xb);
  cvt_w_kernel<<<dim3(1024, 4), dim3(256), 0, stream>>>(Wq, Wk, Wv, Wo, wb);
  gemm_qkv_kernel<<<dim3(8, 32, 3), dim3(256), 0, stream>>>(xb, wb, bq, bk, bv, qkv);
  attn_kernel<<<dim3(32, 32), dim3(256), 0, stream>>>(
      qkv, qkv + (size_t)4096 * DM, qkv + (size_t)2 * 4096 * DM, ob);
  gemm_out_kernel<<<dim3(8, 32), dim3(256), 0, stream>>>(
      ob, wb + (size_t)3 * DM * DM, bo, (float*)d_out);
}